// Round 1
// 330.564 us; speedup vs baseline: 1.0909x; 1.0909x over previous
//
#include <hip/hip_runtime.h>
#include <cmath>

// Problem constants (from reference)
#define NN  5      // N_NODES
#define BB  4      // batch
#define CCH 256    // channels
#define HWD 1024   // H*W
#define THRESH_V 0.3f
#define EPS_V 1e-12f

// Tile config: block = 384 threads = 6 waves. Block computes a 64x64 output
// tile (64 channels x 64 hw) for node i, batch b. Wave w<5 computes stream
// A[i]@x[w]; wave 5 computes W2[i]@x[i]. Each wave owns the full 64x64 tile
// of its stream with an 8x8 per-lane fragment -> 4 ds_read_b128 per 64 FMAs
// (2x the FLOP/LDS-instr of the previous 4x4-frag kernel, which was
// LDS-read-pipe bound at ~307us of 343us).
#define CT 64      // channel rows per block
#define WT 64      // hw cols per block
#define KC 32      // k chunk
#define APAD 68    // padded LDS row stride (floats) for A/W2, 16B-aligned rows
#define SPAD 68    // Es row stride (floats) in epilogue

// smem layout (floats):
//   staging: Xs[5][32][64] @0 (10240) | As[32][68] @10240 (2176) | W2s @12416 (2176)
//   epilogue overlay: Es[6][32][68] @0 (13056)
#define XS_FLOATS (NN * KC * WT)          // 10240
#define AS_OFF    XS_FLOATS               // 10240
#define W2_OFF    (AS_OFF + KC * APAD)    // 12416
#define SMEM_FLOATS (W2_OFF + KC * APAD)  // 14592 floats = 58368 B (2 blocks/CU)

__global__ __launch_bounds__(384, 3)
void fub_main(const float* __restrict__ x, const float* __restrict__ wmat,
              const float* __restrict__ conv_w, const float* __restrict__ conv_b,
              float* __restrict__ out)
{
    __shared__ __align__(16) float smem[SMEM_FLOATS];
    float* Xs  = smem;            // [5][KC][WT]
    float* As  = smem + AS_OFF;   // [KC][APAD], As[k][r] = W1[i][c0+r][k]+W2[...]
    float* W2s = smem + W2_OFF;   // [KC][APAD]
    float* Es  = smem;            // [6][32][SPAD] overlay (epilogue only)

    const int tid  = threadIdx.x;
    const int wv   = tid >> 6;        // 0..5 : stream id
    const int lane = tid & 63;

    int bid = blockIdx.x;
    const int hwt = bid & 15; bid >>= 4;   // 16 hw tiles of 64
    const int b   = bid & 3;  bid >>= 2;   // 4 batches
    const int ct  = bid & 3;  bid >>= 2;   // 4 channel tiles of 64
    const int i   = bid;                   // 0..4

    const int c0  = ct * CT;
    const int hw0 = hwt * WT;

    const int lr = (lane >> 3) << 3;  // frag row base 0,8,...,56
    const int lc = (lane & 7)  << 3;  // frag col base 0,8,...,56

    // stream w<5 multiplies A by x[w]; stream 5 multiplies W2 by x[i]
    const int jx = (wv < 5) ? wv : i;
    const float* M  = (wv == 5) ? W2s : As;
    const float* Mb = M + lr;
    const float* Xb = Xs + jx * (KC * WT) + lc;

    float acc[8][8];
#pragma unroll
    for (int r = 0; r < 8; ++r)
#pragma unroll
        for (int c = 0; c < 8; ++c) acc[r][c] = 0.0f;

    for (int k0 = 0; k0 < CCH; k0 += KC) {
        // ---- stage: threads 0..255 load Xs (2560 float4), 256..383 load A/W2 ----
        if (tid < 256) {
#pragma unroll
            for (int it = 0; it < 10; ++it) {
                const int t   = tid + it * 256;       // 0..2559
                const int j   = t >> 9;               // 0..4
                const int rem = t & 511;
                const int kk  = rem >> 4;             // 0..31
                const int q4  = (rem & 15) << 2;      // 0..60
                const float4 v = *(const float4*)(
                    x + (size_t)((j * BB + b) * CCH + k0 + kk) * HWD + hw0 + q4);
                *(float4*)(Xs + j * (KC * WT) + kk * WT + q4) = v;
            }
        } else {
            const int u   = tid - 256;                // 0..127
            const int rq  = u >> 3;                   // 0..15 : 4-row group
            const int kq4 = (u & 7) << 2;             // 0..28 : k quad base
            const int rb  = rq << 2;                  // row base 0..60
            const float* base0 =
                conv_w + (size_t)(i * CCH + c0 + rb) * (2 * CCH) + k0 + kq4;
            float4 w1[4], w2[4];
#pragma unroll
            for (int rr = 0; rr < 4; ++rr) {
                w1[rr] = *(const float4*)(base0 + rr * (2 * CCH));
                w2[rr] = *(const float4*)(base0 + rr * (2 * CCH) + CCH);
            }
            // transpose in registers -> float4 LDS stores along rows
            *(float4*)(As + (kq4 + 0) * APAD + rb) = make_float4(
                w1[0].x + w2[0].x, w1[1].x + w2[1].x, w1[2].x + w2[2].x, w1[3].x + w2[3].x);
            *(float4*)(As + (kq4 + 1) * APAD + rb) = make_float4(
                w1[0].y + w2[0].y, w1[1].y + w2[1].y, w1[2].y + w2[2].y, w1[3].y + w2[3].y);
            *(float4*)(As + (kq4 + 2) * APAD + rb) = make_float4(
                w1[0].z + w2[0].z, w1[1].z + w2[1].z, w1[2].z + w2[2].z, w1[3].z + w2[3].z);
            *(float4*)(As + (kq4 + 3) * APAD + rb) = make_float4(
                w1[0].w + w2[0].w, w1[1].w + w2[1].w, w1[2].w + w2[2].w, w1[3].w + w2[3].w);
            *(float4*)(W2s + (kq4 + 0) * APAD + rb) = make_float4(w2[0].x, w2[1].x, w2[2].x, w2[3].x);
            *(float4*)(W2s + (kq4 + 1) * APAD + rb) = make_float4(w2[0].y, w2[1].y, w2[2].y, w2[3].y);
            *(float4*)(W2s + (kq4 + 2) * APAD + rb) = make_float4(w2[0].z, w2[1].z, w2[2].z, w2[3].z);
            *(float4*)(W2s + (kq4 + 3) * APAD + rb) = make_float4(w2[0].w, w2[1].w, w2[2].w, w2[3].w);
        }
        __syncthreads();

        // ---- compute: each wave does its stream's 64x64 tile, 8x8 frag/lane ----
#pragma unroll 4
        for (int kk = 0; kk < KC; ++kk) {
            const float4 a0  = *(const float4*)(Mb + kk * APAD);
            const float4 a1  = *(const float4*)(Mb + kk * APAD + 4);
            const float4 xv0 = *(const float4*)(Xb + kk * WT);
            const float4 xv1 = *(const float4*)(Xb + kk * WT + 4);
            const float ar[8] = {a0.x, a0.y, a0.z, a0.w, a1.x, a1.y, a1.z, a1.w};
            const float xc[8] = {xv0.x, xv0.y, xv0.z, xv0.w, xv1.x, xv1.y, xv1.z, xv1.w};
#pragma unroll
            for (int r = 0; r < 8; ++r)
#pragma unroll
                for (int c = 0; c < 8; ++c)
                    acc[r][c] = fmaf(ar[r], xc[c], acc[r][c]);
        }
        __syncthreads();
    }

    // ---- epilogue: 2 passes over 32-row halves; exchange streams via LDS ----
    const int rhme  = lr >> 5;        // which row-half this lane's frag is in
    const int rbase = lr & 31;

#pragma unroll
    for (int rh = 0; rh < 2; ++rh) {
        if (rhme == rh) {
            float* Eb = Es + wv * (32 * SPAD) + lc;
#pragma unroll
            for (int r = 0; r < 8; ++r) {
                *(float4*)(Eb + (rbase + r) * SPAD) =
                    make_float4(acc[r][0], acc[r][1], acc[r][2], acc[r][3]);
                *(float4*)(Eb + (rbase + r) * SPAD + 4) =
                    make_float4(acc[r][4], acc[r][5], acc[r][6], acc[r][7]);
            }
        }
        __syncthreads();

        if (tid < 256) {
            const int row = tid >> 3;           // 0..31
            const int c   = c0 + rh * 32 + row;
            const float bias = conv_b[i * CCH + c];

            float wrow[NN];
#pragma unroll
            for (int j = 0; j < NN; ++j) wrow[j] = wmat[i * NN + j];

            const int colA = (tid & 7) << 2;    // 0..28
#pragma unroll
            for (int half = 0; half < 2; ++half) {
                const int col = colA + (half << 5);   // 0..28 / 32..60

                const float4 T = *(const float4*)(Es + 5 * (32 * SPAD) + row * SPAD + col);
                const float Tv[4] = {T.x, T.y, T.z, T.w};

                float num[4] = {0.f, 0.f, 0.f, 0.f};
                float sq [4] = {0.f, 0.f, 0.f, 0.f};
#pragma unroll
                for (int j = 0; j < NN; ++j) {
                    const float4 s  = *(const float4*)(Es + j * (32 * SPAD) + row * SPAD + col);
                    const float4 xj = *(const float4*)(
                        x + (size_t)((j * BB + b) * CCH + c) * HWD + hw0 + col);
                    const float sv[4] = {s.x, s.y, s.z, s.w};
                    const float xv[4] = {xj.x, xj.y, xj.z, xj.w};
#pragma unroll
                    for (int cc = 0; cc < 4; ++cc) {
                        const float target = sv[cc] + Tv[cc] + bias;
                        const float dist   = xv[cc] - target;
                        const float z      = dist * wrow[j];
                        float e = 1.0f / (1.0f + expf(-z));
                        e = (e > THRESH_V) ? e : 0.0f;
                        sq[cc]  = fmaf(e, e, sq[cc]);
                        num[cc] = fmaf(e, xv[cc], num[cc]);
                    }
                }
                float4 res;
                res.x = num[0] / fmaxf(sqrtf(sq[0]), EPS_V);
                res.y = num[1] / fmaxf(sqrtf(sq[1]), EPS_V);
                res.z = num[2] / fmaxf(sqrtf(sq[2]), EPS_V);
                res.w = num[3] / fmaxf(sqrtf(sq[3]), EPS_V);
                *(float4*)(out + (size_t)((i * BB + b) * CCH + c) * HWD + hw0 + col) = res;
            }
        }
        __syncthreads();
    }
}

extern "C" void kernel_launch(void* const* d_in, const int* in_sizes, int n_in,
                              void* d_out, int out_size, void* d_ws, size_t ws_size,
                              hipStream_t stream) {
    const float* x      = (const float*)d_in[0];
    const float* w      = (const float*)d_in[1];
    const float* conv_w = (const float*)d_in[2];
    const float* conv_b = (const float*)d_in[3];
    float* out = (float*)d_out;

    // grid: i(5) * ct(4) * b(4) * hwt(16) = 1280 blocks of 384 threads
    dim3 grid(1280);
    dim3 block(384);
    fub_main<<<grid, block, 0, stream>>>(x, w, conv_w, conv_b, out);
}